// Round 6
// baseline (886.831 us; speedup 1.0000x reference)
//
#include <hip/hip_runtime.h>

#define B_ 16
#define NF_ 16
#define N_ 1024
#define D_ 128
#define S_ 8
#define SCALE_ 0.08838834764831845f
#define NB 256
#define NT 512
// scalar index into chunk-padded [4][36] vectors (chunk c = i>>5 at offset c*36)
#define CPAD(i) ((((i) >> 5) * 36) + ((i) & 31))

struct SmemA {
  float Xt[64 * 128];       // NORMALIZED x-hat, XOR-swizzled: (j,k4) -> j*128 + ((k4^(j&7))<<2)
  float at[8 * 64];         // dots, then attn (incl +eps)
  float qWs[1024];          // SCALE-prefolded qW, slot-major
  float qbs[8];
};
struct SmemB {              // phase-B scratch
  float Uk[144];            // chunk-padded U vector
  float gh[384];
  float gi[384];
  float hn[128];
  float buf[144], hid[144], nrm[144];
  float red[16];
};

// ---- fence-free device-coherent accessors (proven across 612..483us kernels) ----
__device__ __forceinline__ float gload(const float* p) {
  return __hip_atomic_load(p, __ATOMIC_RELAXED, __HIP_MEMORY_SCOPE_AGENT);
}
__device__ __forceinline__ void gstore(float* p, float v) {
  __hip_atomic_store(p, v, __ATOMIC_RELAXED, __HIP_MEMORY_SCOPE_AGENT);
}
__device__ __forceinline__ void arrive(unsigned* c) {
  __syncthreads();
  if (threadIdx.x == 0) {
    __builtin_amdgcn_s_waitcnt(0);
    __hip_atomic_fetch_add(c, 1u, __ATOMIC_RELAXED, __HIP_MEMORY_SCOPE_AGENT);
  }
}
__device__ __forceinline__ void wait_for(unsigned* c, unsigned target) {
  if (threadIdx.x == 0) {
    while (__hip_atomic_load(c, __ATOMIC_RELAXED, __HIP_MEMORY_SCOPE_AGENT) < target)
      __builtin_amdgcn_s_sleep(1);
  }
  __syncthreads();
}

// LDS-only barrier: orders LDS traffic without draining vmcnt (global loads/stores
// stay in flight across stage boundaries). Guide §5 pattern; sched_barrier pins
// compiler reordering around the asm waitcnt (rule 18).
__device__ __forceinline__ void lbar() {
  __builtin_amdgcn_sched_barrier(0);
  asm volatile("s_waitcnt lgkmcnt(0)" ::: "memory");
  __builtin_amdgcn_s_barrier();
  __builtin_amdgcn_sched_barrier(0);
}

__device__ __forceinline__ float dot128f(const float* __restrict__ wrow, const float* x, float acc) {
  const float4* w = (const float4*)wrow;
#pragma unroll
  for (int i = 0; i < 32; ++i) {
    float4 v = w[i];
    const float4 xv = *(const float4*)(x + i * 4);
    acc += v.x * xv.x + v.y * xv.y + v.z * xv.z + v.w * xv.w;
  }
  return acc;
}

// Block-wide mean/rsqrt over 128 values held by t<128. ALL threads call. LDS-only barriers.
__device__ __forceinline__ void stats128(float v, int t, float* red, float& m, float& inv) {
  lbar();
  float s = (t < 128) ? v : 0.f;
  float s2 = (t < 128) ? v * v : 0.f;
#pragma unroll
  for (int off = 32; off; off >>= 1) { s += __shfl_down(s, off); s2 += __shfl_down(s2, off); }
  if (t == 0)  { red[0] = s; red[2] = s2; }
  if (t == 64) { red[1] = s; red[3] = s2; }
  lbar();
  m = (red[0] + red[1]) * (1.f / 128.f);
  float var = (red[2] + red[3]) * (1.f / 128.f) - m * m;
  inv = rsqrtf(var + 1e-5f);
}

__device__ __forceinline__ float sigm(float x) { return 1.f / (1.f + __expf(-x)); }
__device__ __forceinline__ float tanh_f(float x) { return 1.f - 2.f / (1.f + __expf(2.f * x)); }

// stage NORMALIZED tile (swizzled); runs in the prefetch window (no trailing barrier).
__device__ __forceinline__ void stage_norm(const float4* pf, float* Xt,
                                           float4 g4, float4 b4, int t) {
  float s1[4], s2[4];
#pragma unroll
  for (int i = 0; i < 4; ++i) {
    s1[i] = pf[i].x + pf[i].y + pf[i].z + pf[i].w;
    s2[i] = pf[i].x * pf[i].x + pf[i].y * pf[i].y + pf[i].z * pf[i].z + pf[i].w * pf[i].w;
  }
#pragma unroll
  for (int mk = 16; mk; mk >>= 1) {
#pragma unroll
    for (int i = 0; i < 4; ++i) { s1[i] += __shfl_xor(s1[i], mk); s2[i] += __shfl_xor(s2[i], mk); }
  }
  int kg = t & 31;
#pragma unroll
  for (int i = 0; i < 4; ++i) {
    int r = (t >> 5) + i * 16;
    float m = s1[i] * (1.f / 128.f);
    float inv = rsqrtf(s2[i] * (1.f / 128.f) - m * m + 1e-5f);
    float4 v = pf[i];
    v.x = (v.x - m) * inv * g4.x + b4.x;
    v.y = (v.y - m) * inv * g4.y + b4.y;
    v.z = (v.z - m) * inv * g4.z + b4.z;
    v.w = (v.w - m) * inv * g4.w + b4.w;
    *(float4*)&Xt[r * 128 + ((kg ^ (r & 7)) << 2)] = v;
  }
}

// slot -> LN_sl -> qW = SCALE*(Wqk@nrm + bqk) with PRELOADED Wqk rows in registers
__device__ __forceinline__ void q_project_pub(SmemB& Bm, const float* slot,
    const float* __restrict__ g_sl, const float* __restrict__ be_sl,
    const float4* wqr, const float* __restrict__ bqk,
    const float* __restrict__ wqbk, const float* __restrict__ bqbk,
    float* qW_g, float* qb_g, int b, int sl, int t) {
  float m, inv;
  float sv = (t < 128) ? slot[t] : 0.f;
  stats128(sv, t, Bm.red, m, inv);
  if (t < 128) {
    float nv = (sv - m) * inv * g_sl[t] + be_sl[t];
    Bm.nrm[CPAD(t)] = nv;
    float qp = wqbk[t] * nv;
#pragma unroll
    for (int off = 32; off; off >>= 1) qp += __shfl_down(qp, off);
    if (t == 0)  Bm.red[4] = qp;
    if (t == 64) Bm.red[5] = qp;
  }
  lbar();
  {
    int c = t & 3, r = t >> 2;
    float acc = 0.f;
#pragma unroll
    for (int q = 0; q < 8; ++q) {
      float4 wv = wqr[q];
      float4 vv = *(const float4*)&Bm.nrm[c * 36 + q * 4];
      acc += wv.x * vv.x + wv.y * vv.y + wv.z * vv.z + wv.w * vv.w;
    }
    acc += __shfl_down(acc, 2); acc += __shfl_down(acc, 1);
    if (c == 0) gstore(&qW_g[b * 1024 + sl * 128 + r], (acc + bqk[r]) * SCALE_);
  }
  if (t == 0) gstore(&qb_g[b * 8 + sl], (Bm.red[4] + Bm.red[5] + bqbk[0]) * SCALE_);
}

// one-shot algebraic folds (harness-verified rounds 1-5)
__global__ __launch_bounds__(128) void precomp(
    const float* __restrict__ Wih, const float* __restrict__ bih,
    const float* __restrict__ Wv, const float* __restrict__ bv,
    const float* __restrict__ Wq, const float* __restrict__ bq,
    const float* __restrict__ Wk, const float* __restrict__ bk,
    float* Wiv, float* bihv, float* Wqk, float* bqk, float* wqbk, float* bqbk) {
  __shared__ float r2[2];
  int r = blockIdx.x, t = threadIdx.x;
  if (r < 384) {
    float acc = 0.f;
#pragma unroll 8
    for (int k = 0; k < 128; ++k) acc += Wih[r * 128 + k] * Wv[k * 128 + t];
    Wiv[r * 128 + t] = acc;
    float p = Wih[r * 128 + t] * bv[t];
#pragma unroll
    for (int off = 32; off; off >>= 1) p += __shfl_down(p, off);
    if ((t & 63) == 0) r2[t >> 6] = p;
    __syncthreads();
    if (t == 0) bihv[r] = r2[0] + r2[1] + bih[r];
  } else {
    int c = r - 384;
    float acc = 0.f;
#pragma unroll 8
    for (int dd = 0; dd < 128; ++dd) acc += Wk[dd * 128 + c] * Wq[dd * 128 + t];
    Wqk[c * 128 + t] = acc;
    float p = Wk[t * 128 + c] * bq[t];
#pragma unroll
    for (int off = 32; off; off >>= 1) p += __shfl_down(p, off);
    if ((t & 63) == 0) r2[t >> 6] = p;
    __syncthreads();
    if (t == 0) bqk[c] = r2[0] + r2[1];
    if (c == 0) {
      float a2 = 0.f;
#pragma unroll 8
      for (int dd = 0; dd < 128; ++dd) a2 += Wq[dd * 128 + t] * bk[dd];
      wqbk[t] = a2;
      float p2 = bq[t] * bk[t];
#pragma unroll
      for (int off = 32; off; off >>= 1) p2 += __shfl_down(p2, off);
      __syncthreads();
      if ((t & 63) == 0) r2[t >> 6] = p2;
      __syncthreads();
      if (t == 0) bqbk[0] = r2[0] + r2[1];
    }
  }
}

__global__ __launch_bounds__(NT, 2) void slot_persist(
    const float* __restrict__ x, const float* __restrict__ slots_init,
    const float* __restrict__ Whh, const float* __restrict__ bhh,
    const float* __restrict__ W1, const float* __restrict__ b1,
    const float* __restrict__ W2, const float* __restrict__ b2,
    const float* __restrict__ g_in, const float* __restrict__ be_in,
    const float* __restrict__ g_sl, const float* __restrict__ be_sl,
    const float* __restrict__ g_ff, const float* __restrict__ be_ff,
    const float* __restrict__ Wiv, const float* __restrict__ bihv,
    const float* __restrict__ Wqk, const float* __restrict__ bqk,
    const float* __restrict__ wqbk, const float* __restrict__ bqbk,
    float* out_slots, float* out_attn,
    unsigned* cntA, unsigned* cntB,
    float* U_g, float* SS_g, float* qW_g, float* qb_g) {
  __shared__ __align__(16) SmemA sa;
  __shared__ __align__(16) SmemB sb;
  __shared__ __align__(16) float slot_sh[128];
  int t = threadIdx.x, bid = blockIdx.x;
  int b = bid >> 4, jt = bid & 15;
  bool isB = (jt < 8);
  unsigned* cA = cntA + (b << 6);
  unsigned* cB = cntB + (b << 6);
  int s = t >> 6, j = t & 63;

  const float4 g4 = *(const float4*)(g_in + (t & 31) * 4);
  const float4 b4 = *(const float4*)(be_in + (t & 31) * 4);

  if (isB) {
    if (t < 128) slot_sh[t] = slots_init[jt * 128 + t];
    float4 wqr0[8];
    {
      int c = t & 3, r = t >> 2;
#pragma unroll
      for (int q = 0; q < 8; ++q) wqr0[q] = *(const float4*)(Wqk + r * 128 + c * 32 + q * 4);
    }
    q_project_pub(sb, slot_sh, g_sl, be_sl, wqr0, bqk, wqbk, bqbk, qW_g, qb_g, b, jt, t);
    arrive(cB);
  }
  float4 pf[4];
  {
    const float* xsrc = x + (((long)b * NF_ + 0) * N_ + jt * 64) * D_;
#pragma unroll
    for (int i = 0; i < 4; ++i) {
      int ch = t + i * 512;
      pf[i] = *(const float4*)(xsrc + (ch >> 5) * 128 + (ch & 31) * 4);
    }
  }
  stage_norm(pf, sa.Xt, g4, b4, t);   // frame 0; barrier = loop-top wait_for

  for (int it = 0; it < 17; ++it) {
    int f = (it == 0) ? 0 : it - 1;
    int wo = it > 0;
    int par = it & 1;
    // ---- wait for qW of this frame ----
    wait_for(cB, 8u * (it + 1));
    sa.qWs[t] = gload(&qW_g[b * 1024 + t]);
    sa.qWs[512 + t] = gload(&qW_g[b * 1024 + 512 + t]);
    if (t < 8) sa.qbs[t] = gload(&qb_g[b * 8 + t]);
    lbar();
    // ---- dots on normalized X (conflict-free swizzled b128); SCALE prefolded ----
    {
      const float4* qq4 = (const float4*)(sa.qWs + s * 128);
      float d = 0.f;
#pragma unroll
      for (int k4 = 0; k4 < 32; ++k4) {
        float4 xv = *(const float4*)&sa.Xt[j * 128 + ((k4 ^ (j & 7)) << 2)];
        float4 qv = qq4[k4];
        d += xv.x * qv.x + xv.y * qv.y + xv.z * qv.z + xv.w * qv.w;
      }
      sa.at[s * 64 + j] = d + sa.qbs[s];
    }
    lbar();
    // ---- softmax over slots (per column j = t < 64); stores deferred ----
    float vals[8];
    if (t < 64) {
      float mx = -1e30f;
#pragma unroll
      for (int ss = 0; ss < 8; ++ss) { vals[ss] = sa.at[ss * 64 + t]; mx = fmaxf(mx, vals[ss]); }
      float sum = 0.f;
#pragma unroll
      for (int ss = 0; ss < 8; ++ss) { vals[ss] = __expf(vals[ss] - mx); sum += vals[ss]; }
      float rr = 1.f / sum;
#pragma unroll
      for (int ss = 0; ss < 8; ++ss) { vals[ss] = vals[ss] * rr + 1e-8f; sa.at[ss * 64 + t] = vals[ss]; }
    }
    lbar();
    // ---- SS partials (wave = slot), device atomics ----
    {
      float v = sa.at[s * 64 + j];
#pragma unroll
      for (int off = 32; off; off >>= 1) v += __shfl_down(v, off);
      if (j == 0) atomicAdd(&SS_g[(b * 2 + par) * 8 + s], v);
    }
    // ---- U partials: thread = (slot s, kq float4-col, jh half); b128 X reads ----
    {
      int kq = j & 31, jh = j >> 5;
      float4 acc = {0.f, 0.f, 0.f, 0.f};
      const float* a0 = sa.at + s * 64 + jh * 32;
#pragma unroll
      for (int jj = 0; jj < 32; ++jj) {
        int jr = jh * 32 + jj;
        float av = a0[jj];
        float4 xv = *(const float4*)&sa.Xt[jr * 128 + ((kq ^ (jr & 7)) << 2)];
        acc.x += av * xv.x; acc.y += av * xv.y; acc.z += av * xv.z; acc.w += av * xv.w;
      }
      acc.x += __shfl_down(acc.x, 32); acc.y += __shfl_down(acc.y, 32);
      acc.z += __shfl_down(acc.z, 32); acc.w += __shfl_down(acc.w, 32);
      if (jh == 0) {
        float* Ub = U_g + ((b * 2 + par) << 10) + s * 128 + kq * 4;
        atomicAdd(&Ub[0], acc.x); atomicAdd(&Ub[1], acc.y);
        atomicAdd(&Ub[2], acc.z); atomicAdd(&Ub[3], acc.w);
      }
    }
    arrive(cA);
    // ---- deferred attn stores (in flight across B-chain / prefetch; lbar won't drain) ----
    if (wo && t < 64) {
#pragma unroll
      for (int ss = 0; ss < 8; ++ss)
        out_attn[(((long)b * NF_ + f) * S_ + ss) * N_ + jt * 64 + t] = vals[ss];
    }
    // ================= phase B (blocks jt<8: slot s=jt of batch b) =================
    if (isB) {
      int sl = jt;
      // --- preload Wiv (stage 2) + W1 (stage 5) rows; L2 stream overlaps hop+stage1 ---
      float4 wivr[24], w1r[8];
      {
        int c = t & 3, rb = t >> 2;
#pragma unroll
        for (int g = 0; g < 3; ++g)
#pragma unroll
          for (int q = 0; q < 8; ++q)
            wivr[g * 8 + q] = *(const float4*)(Wiv + (long)(rb + g * 128) * 128 + c * 32 + q * 4);
#pragma unroll
        for (int q = 0; q < 8; ++q)
          w1r[q] = *(const float4*)(W1 + rb * 128 + c * 32 + q * 4);
      }
      wait_for(cA, 16u * (it + 1));
      float* Ub = U_g + ((b * 2 + par) << 10) + sl * 128;
      float* ssb = SS_g + (b * 2 + par) * 8;
      // stage 1: read U + SS, zero them (t<128) | gh = Whh@hprev + bhh (t>=128)
      if (t < 128) {
        float uv = gload(&Ub[t]);
        sb.Uk[CPAD(t)] = uv;
        gstore(&Ub[t], 0.f);
        if (t == 0) { sb.red[14] = gload(&ssb[sl]); gstore(&ssb[sl], 0.f); }
      } else {
        int r = t - 128;
        sb.gh[r] = dot128f(Whh + (long)r * 128, slot_sh, bhh[r]);
      }
      lbar();
      // stage 2: gi_raw = Wiv @ U from preloaded registers (k-split, shfl reduce)
      {
        int c = t & 3;
        float4 uv[8];
#pragma unroll
        for (int q = 0; q < 8; ++q) uv[q] = *(const float4*)&sb.Uk[c * 36 + q * 4];
#pragma unroll
        for (int g = 0; g < 3; ++g) {
          float acc = 0.f;
#pragma unroll
          for (int q = 0; q < 8; ++q) {
            float4 wv = wivr[g * 8 + q];
            acc += wv.x * uv[q].x + wv.y * uv[q].y + wv.z * uv[q].z + wv.w * uv[q].w;
          }
          acc += __shfl_down(acc, 2); acc += __shfl_down(acc, 1);
          if (c == 0) sb.gi[(t >> 2) + g * 128] = acc;
        }
      }
      // --- issue W2 preload (Wiv regs now dead) + next-frame x prefetch ---
      float4 w2r[8];
      {
        int c = t & 3, r = t >> 2;
#pragma unroll
        for (int q = 0; q < 8; ++q)
          w2r[q] = *(const float4*)(W2 + r * 128 + c * 32 + q * 4);
      }
      if (it && it < 16) {
        const float* xsrc = x + (((long)b * NF_ + it) * N_ + jt * 64) * D_;
#pragma unroll
        for (int i = 0; i < 4; ++i) {
          int ch = t + i * 512;
          pf[i] = *(const float4*)(xsrc + (ch >> 5) * 128 + (ch & 31) * 4);
        }
      }
      lbar();
      // stage 3: gates -> hn  (gi = gi_raw/SS + bihv)
      float hnew = 0.f;
      if (t < 128) {
        float invss = 1.f / sb.red[14];
        float gr = sigm(sb.gi[t] * invss + bihv[t] + sb.gh[t]);
        float gz = sigm(sb.gi[128 + t] * invss + bihv[128 + t] + sb.gh[128 + t]);
        float gn = tanh_f(sb.gi[256 + t] * invss + bihv[256 + t] + gr * sb.gh[256 + t]);
        hnew = (1.f - gz) * gn + gz * slot_sh[t];
        sb.hn[t] = hnew;
      }
      // stage 4: LN_ff(hn) -> buf  (stats128 has internal lbars)
      float m, inv;
      stats128(hnew, t, sb.red, m, inv);
      if (t < 128) sb.buf[CPAD(t)] = (hnew - m) * inv * g_ff[t] + be_ff[t];
      // --- issue Wqk preload for stage 7 ---
      float4 wqr[8];
      if (it < 16) {
        int c = t & 3, r = t >> 2;
#pragma unroll
        for (int q = 0; q < 8; ++q)
          wqr[q] = *(const float4*)(Wqk + r * 128 + c * 32 + q * 4);
      }
      lbar();
      // stage 5: hid = relu(W1@buf + b1)  (preloaded W1)
      {
        int c = t & 3, r = t >> 2;
        float acc = 0.f;
#pragma unroll
        for (int q = 0; q < 8; ++q) {
          float4 wv = w1r[q];
          float4 vv = *(const float4*)&sb.buf[c * 36 + q * 4];
          acc += wv.x * vv.x + wv.y * vv.y + wv.z * vv.z + wv.w * vv.w;
        }
        acc += __shfl_down(acc, 2); acc += __shfl_down(acc, 1);
        if (c == 0) sb.hid[CPAD(r)] = fmaxf(acc + b1[r], 0.f);
      }
      lbar();
      // stage 6: sn = hn + W2@hid + b2  (preloaded W2) -> slot_sh
      {
        int c = t & 3, r = t >> 2;
        float acc = 0.f;
#pragma unroll
        for (int q = 0; q < 8; ++q) {
          float4 wv = w2r[q];
          float4 vv = *(const float4*)&sb.hid[c * 36 + q * 4];
          acc += wv.x * vv.x + wv.y * vv.y + wv.z * vv.z + wv.w * vv.w;
        }
        acc += __shfl_down(acc, 2); acc += __shfl_down(acc, 1);
        if (c == 0) slot_sh[r] = sb.hn[r] + acc + b2[r];
      }
      // stage 7: next-frame q projection (preloaded Wqk) + announce
      if (it < 16) {
        q_project_pub(sb, slot_sh, g_sl, be_sl, wqr, bqk, wqbk, bqbk, qW_g, qb_g, b, sl, t);
        arrive(cB);
      } else {
        lbar();
      }
      // deferred slots store
      if (wo && t < 128)
        out_slots[(((long)b * NF_ + f) * S_ + sl) * D_ + t] = slot_sh[t];
      // stage next frame (pf loads issued back at stage 2 -> latency long hidden)
      if (it && it < 16) stage_norm(pf, sa.Xt, g4, b4, t);
    } else {
      // non-B: prefetch + stage next frame while B-chain runs
      if (it && it < 16) {
        const float* xsrc = x + (((long)b * NF_ + it) * N_ + jt * 64) * D_;
#pragma unroll
        for (int i = 0; i < 4; ++i) {
          int ch = t + i * 512;
          pf[i] = *(const float4*)(xsrc + (ch >> 5) * 128 + (ch & 31) * 4);
        }
        stage_norm(pf, sa.Xt, g4, b4, t);
      }
    }
  }
}

extern "C" void kernel_launch(void* const* d_in, const int* in_sizes, int n_in,
                              void* d_out, int out_size, void* d_ws, size_t ws_size,
                              hipStream_t stream) {
  const float* inputs     = (const float*)d_in[0];
  const float* slots_init = (const float*)d_in[1];
  const float* Wq  = (const float*)d_in[2];
  const float* bq  = (const float*)d_in[3];
  const float* Wk  = (const float*)d_in[4];
  const float* bk  = (const float*)d_in[5];
  const float* Wv  = (const float*)d_in[6];
  const float* bv  = (const float*)d_in[7];
  const float* W1  = (const float*)d_in[8];
  const float* b1  = (const float*)d_in[9];
  const float* W2  = (const float*)d_in[10];
  const float* b2  = (const float*)d_in[11];
  const float* Wih = (const float*)d_in[12];
  const float* Whh = (const float*)d_in[13];
  const float* bih = (const float*)d_in[14];
  const float* bhh = (const float*)d_in[15];
  const float* g_in  = (const float*)d_in[16];
  const float* be_in = (const float*)d_in[17];
  const float* g_sl  = (const float*)d_in[18];
  const float* be_sl = (const float*)d_in[19];
  const float* g_ff  = (const float*)d_in[20];
  const float* be_ff = (const float*)d_in[21];

  float* out_slots = (float*)d_out;
  float* out_attn  = out_slots + (size_t)B_ * NF_ * S_ * D_;

  char* ws = (char*)d_ws;
  unsigned* cntA = (unsigned*)ws;                    // 16 counters, 256 B apart (4 KB)
  unsigned* cntB = (unsigned*)(ws + 4096);           // 4 KB
  float* U_g   = (float*)(ws + 8192);                // [16][2][1024] = 131072 -> 139264
  float* SS_g  = (float*)(ws + 139264);              // [16][2][8]    = 1024   -> 140288
  float* Wiv   = (float*)(ws + 140288);              // 196608 -> 336896
  float* bihv  = (float*)(ws + 336896);              // 1536   -> 338432
  float* WqkW  = (float*)(ws + 338432);              // 65536  -> 403968
  float* bqk   = (float*)(ws + 403968);              // 512    -> 404480
  float* wqbk  = (float*)(ws + 404480);              // 512    -> 404992
  float* bqbk  = (float*)(ws + 404992);              // 256    -> 405248
  float* qW_g  = (float*)(ws + 405248);              // 65536  -> 470784
  float* qb_g  = (float*)(ws + 470784);              // 512    -> 471296

  hipMemsetAsync(d_ws, 0, 140288, stream);  // counters + U/SS accumulators

  precomp<<<512, 128, 0, stream>>>(Wih, bih, Wv, bv, Wq, bq, Wk, bk,
                                   Wiv, bihv, WqkW, bqk, wqbk, bqbk);
  slot_persist<<<NB, NT, 0, stream>>>(inputs, slots_init, Whh, bhh,
      W1, b1, W2, b2, g_in, be_in, g_sl, be_sl, g_ff, be_ff,
      Wiv, bihv, WqkW, bqk, wqbk, bqbk,
      out_slots, out_attn, cntA, cntB, U_g, SS_g, qW_g, qb_g);
}

// Round 7
// 736.727 us; speedup vs baseline: 1.2037x; 1.2037x over previous
//
#include <hip/hip_runtime.h>

#define B_ 16
#define NF_ 16
#define N_ 1024
#define D_ 128
#define S_ 8
#define SCALE_ 0.08838834764831845f
#define NB 256
#define NT 512
// scalar index into chunk-padded [4][36] vectors (chunk c = i>>5 at offset c*36)
#define CPAD(i) ((((i) >> 5) * 36) + ((i) & 31))
// full 5-bit XOR swizzle: logical float4-group k of row r lives at group ((k^r)&31)
#define XSW(r, k) (((r) * 128) + ((((k) ^ (r)) & 31) << 2))

struct SmemA {
  float Xt[64 * 128];       // NORMALIZED x-hat, swizzled per XSW
  float at[8 * 64];         // dots, then attn (incl +eps)
  float qWs[1024];          // SCALE-prefolded qW, slot-major
  float qbs[8];
};
struct SmemB {              // phase-B scratch
  float Uk[144];            // chunk-padded U vector
  float gh[384];
  float gi[384];
  float hn[128];
  float buf[144], hid[144], nrm[144];
  float red[16];
};

// ---- fence-free device-coherent accessors (proven across 612..483us kernels) ----
__device__ __forceinline__ float gload(const float* p) {
  return __hip_atomic_load(p, __ATOMIC_RELAXED, __HIP_MEMORY_SCOPE_AGENT);
}
__device__ __forceinline__ void gstore(float* p, float v) {
  __hip_atomic_store(p, v, __ATOMIC_RELAXED, __HIP_MEMORY_SCOPE_AGENT);
}
__device__ __forceinline__ void arrive(unsigned* c) {
  __syncthreads();
  if (threadIdx.x == 0) {
    __builtin_amdgcn_s_waitcnt(0);
    __hip_atomic_fetch_add(c, 1u, __ATOMIC_RELAXED, __HIP_MEMORY_SCOPE_AGENT);
  }
}
__device__ __forceinline__ void wait_for(unsigned* c, unsigned target) {
  if (threadIdx.x == 0) {
    while (__hip_atomic_load(c, __ATOMIC_RELAXED, __HIP_MEMORY_SCOPE_AGENT) < target)
      __builtin_amdgcn_s_sleep(1);
  }
  __syncthreads();
}

// LDS-only barrier: orders LDS traffic without draining vmcnt (global loads/stores
// stay in flight across stage boundaries). Validated functionally in round 6.
__device__ __forceinline__ void lbar() {
  __builtin_amdgcn_sched_barrier(0);
  asm volatile("s_waitcnt lgkmcnt(0)" ::: "memory");
  __builtin_amdgcn_s_barrier();
  __builtin_amdgcn_sched_barrier(0);
}

__device__ __forceinline__ float dot128f(const float* __restrict__ wrow, const float* x, float acc) {
  const float4* w = (const float4*)wrow;
#pragma unroll
  for (int i = 0; i < 32; ++i) {
    float4 v = w[i];
    const float4 xv = *(const float4*)(x + i * 4);
    acc += v.x * xv.x + v.y * xv.y + v.z * xv.z + v.w * xv.w;
  }
  return acc;
}

// Block-wide mean/rsqrt over 128 values held by t<128. ALL threads call.
__device__ __forceinline__ void stats128(float v, int t, float* red, float& m, float& inv) {
  lbar();
  float s = (t < 128) ? v : 0.f;
  float s2 = (t < 128) ? v * v : 0.f;
#pragma unroll
  for (int off = 32; off; off >>= 1) { s += __shfl_down(s, off); s2 += __shfl_down(s2, off); }
  if (t == 0)  { red[0] = s; red[2] = s2; }
  if (t == 64) { red[1] = s; red[3] = s2; }
  lbar();
  m = (red[0] + red[1]) * (1.f / 128.f);
  float var = (red[2] + red[3]) * (1.f / 128.f) - m * m;
  inv = rsqrtf(var + 1e-5f);
}

__device__ __forceinline__ float sigm(float x) { return 1.f / (1.f + __expf(-x)); }
__device__ __forceinline__ float tanh_f(float x) { return 1.f - 2.f / (1.f + __expf(2.f * x)); }

// stage NORMALIZED tile (swizzled); runs in the prefetch window (no trailing barrier).
__device__ __forceinline__ void stage_norm(const float4* pf, float* Xt,
                                           float4 g4, float4 b4, int t) {
  float s1[4], s2[4];
#pragma unroll
  for (int i = 0; i < 4; ++i) {
    s1[i] = pf[i].x + pf[i].y + pf[i].z + pf[i].w;
    s2[i] = pf[i].x * pf[i].x + pf[i].y * pf[i].y + pf[i].z * pf[i].z + pf[i].w * pf[i].w;
  }
#pragma unroll
  for (int mk = 16; mk; mk >>= 1) {
#pragma unroll
    for (int i = 0; i < 4; ++i) { s1[i] += __shfl_xor(s1[i], mk); s2[i] += __shfl_xor(s2[i], mk); }
  }
  int kg = t & 31;
#pragma unroll
  for (int i = 0; i < 4; ++i) {
    int r = (t >> 5) + i * 16;
    float m = s1[i] * (1.f / 128.f);
    float inv = rsqrtf(s2[i] * (1.f / 128.f) - m * m + 1e-5f);
    float4 v = pf[i];
    v.x = (v.x - m) * inv * g4.x + b4.x;
    v.y = (v.y - m) * inv * g4.y + b4.y;
    v.z = (v.z - m) * inv * g4.z + b4.z;
    v.w = (v.w - m) * inv * g4.w + b4.w;
    *(float4*)&Xt[XSW(r, kg)] = v;
  }
}

// slot -> LN_sl -> qW = SCALE*(Wqk@nrm + bqk); k-split matvec streaming Wqk from L2
__device__ void q_project_pub(SmemB& Bm, const float* slot,
    const float* __restrict__ g_sl, const float* __restrict__ be_sl,
    const float* __restrict__ Wqk, const float* __restrict__ bqk,
    const float* __restrict__ wqbk, const float* __restrict__ bqbk,
    float* qW_g, float* qb_g, int b, int sl, int t) {
  float m, inv;
  float sv = (t < 128) ? slot[t] : 0.f;
  stats128(sv, t, Bm.red, m, inv);
  if (t < 128) {
    float nv = (sv - m) * inv * g_sl[t] + be_sl[t];
    Bm.nrm[CPAD(t)] = nv;
    float qp = wqbk[t] * nv;
#pragma unroll
    for (int off = 32; off; off >>= 1) qp += __shfl_down(qp, off);
    if (t == 0)  Bm.red[4] = qp;
    if (t == 64) Bm.red[5] = qp;
  }
  lbar();
  {
    int c = t & 3, r = t >> 2;
    const float4* wr = (const float4*)(Wqk + r * 128 + c * 32);
    float acc = 0.f;
#pragma unroll
    for (int q = 0; q < 8; ++q) {
      float4 wv = wr[q];
      float4 vv = *(const float4*)&Bm.nrm[c * 36 + q * 4];
      acc += wv.x * vv.x + wv.y * vv.y + wv.z * vv.z + wv.w * vv.w;
    }
    acc += __shfl_down(acc, 2); acc += __shfl_down(acc, 1);
    if (c == 0) gstore(&qW_g[b * 1024 + sl * 128 + r], (acc + bqk[r]) * SCALE_);
  }
  if (t == 0) gstore(&qb_g[b * 8 + sl], (Bm.red[4] + Bm.red[5] + bqbk[0]) * SCALE_);
}

// one-shot algebraic folds (harness-verified rounds 1-6)
__global__ __launch_bounds__(128) void precomp(
    const float* __restrict__ Wih, const float* __restrict__ bih,
    const float* __restrict__ Wv, const float* __restrict__ bv,
    const float* __restrict__ Wq, const float* __restrict__ bq,
    const float* __restrict__ Wk, const float* __restrict__ bk,
    float* Wiv, float* bihv, float* Wqk, float* bqk, float* wqbk, float* bqbk) {
  __shared__ float r2[2];
  int r = blockIdx.x, t = threadIdx.x;
  if (r < 384) {
    float acc = 0.f;
#pragma unroll 8
    for (int k = 0; k < 128; ++k) acc += Wih[r * 128 + k] * Wv[k * 128 + t];
    Wiv[r * 128 + t] = acc;
    float p = Wih[r * 128 + t] * bv[t];
#pragma unroll
    for (int off = 32; off; off >>= 1) p += __shfl_down(p, off);
    if ((t & 63) == 0) r2[t >> 6] = p;
    __syncthreads();
    if (t == 0) bihv[r] = r2[0] + r2[1] + bih[r];
  } else {
    int c = r - 384;
    float acc = 0.f;
#pragma unroll 8
    for (int dd = 0; dd < 128; ++dd) acc += Wk[dd * 128 + c] * Wq[dd * 128 + t];
    Wqk[c * 128 + t] = acc;
    float p = Wk[t * 128 + c] * bq[t];
#pragma unroll
    for (int off = 32; off; off >>= 1) p += __shfl_down(p, off);
    if ((t & 63) == 0) r2[t >> 6] = p;
    __syncthreads();
    if (t == 0) bqk[c] = r2[0] + r2[1];
    if (c == 0) {
      float a2 = 0.f;
#pragma unroll 8
      for (int dd = 0; dd < 128; ++dd) a2 += Wq[dd * 128 + t] * bk[dd];
      wqbk[t] = a2;
      float p2 = bq[t] * bk[t];
#pragma unroll
      for (int off = 32; off; off >>= 1) p2 += __shfl_down(p2, off);
      __syncthreads();
      if ((t & 63) == 0) r2[t >> 6] = p2;
      __syncthreads();
      if (t == 0) bqbk[0] = r2[0] + r2[1];
    }
  }
}

__global__ __launch_bounds__(NT) void slot_persist(
    const float* __restrict__ x, const float* __restrict__ slots_init,
    const float* __restrict__ Whh, const float* __restrict__ bhh,
    const float* __restrict__ W1, const float* __restrict__ b1,
    const float* __restrict__ W2, const float* __restrict__ b2,
    const float* __restrict__ g_in, const float* __restrict__ be_in,
    const float* __restrict__ g_sl, const float* __restrict__ be_sl,
    const float* __restrict__ g_ff, const float* __restrict__ be_ff,
    const float* __restrict__ Wiv, const float* __restrict__ bihv,
    const float* __restrict__ Wqk, const float* __restrict__ bqk,
    const float* __restrict__ wqbk, const float* __restrict__ bqbk,
    float* out_slots, float* out_attn,
    unsigned* cntA, unsigned* cntB,
    float* U_g, float* SS_g, float* qW_g, float* qb_g) {
  __shared__ __align__(16) SmemA sa;
  __shared__ __align__(16) SmemB sb;
  __shared__ __align__(16) float slot_sh[128];
  int t = threadIdx.x, bid = blockIdx.x;
  int b = bid >> 4, jt = bid & 15;
  bool isB = (jt < 8);
  unsigned* cA = cntA + (b << 6);
  unsigned* cB = cntB + (b << 6);
  int s = t >> 6, j = t & 63;

  const float4 g4 = *(const float4*)(g_in + (t & 31) * 4);
  const float4 b4 = *(const float4*)(be_in + (t & 31) * 4);

  if (isB) {
    if (t < 128) slot_sh[t] = slots_init[jt * 128 + t];
    q_project_pub(sb, slot_sh, g_sl, be_sl, Wqk, bqk, wqbk, bqbk, qW_g, qb_g, b, jt, t);
    arrive(cB);
  }
  float4 pf[4];
  {
    const float* xsrc = x + (((long)b * NF_ + 0) * N_ + jt * 64) * D_;
#pragma unroll
    for (int i = 0; i < 4; ++i) {
      int ch = t + i * 512;
      pf[i] = *(const float4*)(xsrc + (ch >> 5) * 128 + (ch & 31) * 4);
    }
  }
  stage_norm(pf, sa.Xt, g4, b4, t);   // frame 0; barrier = loop-top wait_for

  for (int it = 0; it < 17; ++it) {
    int f = (it == 0) ? 0 : it - 1;
    int wo = it > 0;
    int par = it & 1;
    // ---- wait for qW of this frame ----
    wait_for(cB, 8u * (it + 1));
    sa.qWs[t] = gload(&qW_g[b * 1024 + t]);
    sa.qWs[512 + t] = gload(&qW_g[b * 1024 + 512 + t]);
    if (t < 8) sa.qbs[t] = gload(&qb_g[b * 8 + t]);
    lbar();
    // ---- dots on normalized X (2-way-free full-XOR b128); SCALE prefolded ----
    {
      const float4* qq4 = (const float4*)(sa.qWs + s * 128);
      float d = 0.f;
#pragma unroll
      for (int k4 = 0; k4 < 32; ++k4) {
        float4 xv = *(const float4*)&sa.Xt[XSW(j, k4)];
        float4 qv = qq4[k4];
        d += xv.x * qv.x + xv.y * qv.y + xv.z * qv.z + xv.w * qv.w;
      }
      sa.at[s * 64 + j] = d + sa.qbs[s];
    }
    lbar();
    // ---- softmax over slots (per column j = t < 64); stores deferred ----
    float vals[8];
    if (t < 64) {
      float mx = -1e30f;
#pragma unroll
      for (int ss = 0; ss < 8; ++ss) { vals[ss] = sa.at[ss * 64 + t]; mx = fmaxf(mx, vals[ss]); }
      float sum = 0.f;
#pragma unroll
      for (int ss = 0; ss < 8; ++ss) { vals[ss] = __expf(vals[ss] - mx); sum += vals[ss]; }
      float rr = 1.f / sum;
#pragma unroll
      for (int ss = 0; ss < 8; ++ss) { vals[ss] = vals[ss] * rr + 1e-8f; sa.at[ss * 64 + t] = vals[ss]; }
    }
    lbar();
    // ---- SS partials (wave = slot), device atomics ----
    {
      float v = sa.at[s * 64 + j];
#pragma unroll
      for (int off = 32; off; off >>= 1) v += __shfl_down(v, off);
      if (j == 0) atomicAdd(&SS_g[(b * 2 + par) * 8 + s], v);
    }
    // ---- U partials: thread = (slot s, kq, j-half); conflict-free b128 X reads ----
    {
      int kq = j & 31, jh = j >> 5;
      float4 acc = {0.f, 0.f, 0.f, 0.f};
      const float* a0 = sa.at + s * 64 + jh * 32;
#pragma unroll
      for (int jj = 0; jj < 32; ++jj) {
        int jr = jh * 32 + jj;
        float av = a0[jj];
        float4 xv = *(const float4*)&sa.Xt[XSW(jr, kq)];
        acc.x += av * xv.x; acc.y += av * xv.y; acc.z += av * xv.z; acc.w += av * xv.w;
      }
      acc.x += __shfl_down(acc.x, 32); acc.y += __shfl_down(acc.y, 32);
      acc.z += __shfl_down(acc.z, 32); acc.w += __shfl_down(acc.w, 32);
      if (jh == 0) {
        float* Ub = U_g + ((b * 2 + par) << 10) + s * 128 + kq * 4;
        atomicAdd(&Ub[0], acc.x); atomicAdd(&Ub[1], acc.y);
        atomicAdd(&Ub[2], acc.z); atomicAdd(&Ub[3], acc.w);
      }
    }
    arrive(cA);
    // ---- deferred attn stores (drained during the next wait's poll) ----
    if (wo && t < 64) {
#pragma unroll
      for (int ss = 0; ss < 8; ++ss)
        out_attn[(((long)b * NF_ + f) * S_ + ss) * N_ + jt * 64 + t] = vals[ss];
    }
    // ================= phase B (blocks jt<8: slot s=jt of batch b) =================
    if (isB) {
      int sl = jt;
      // issue next-frame x loads NOW: latency hides under the poll + B-chain
      if (it && it < 16) {
        const float* xsrc = x + (((long)b * NF_ + it) * N_ + jt * 64) * D_;
#pragma unroll
        for (int i = 0; i < 4; ++i) {
          int ch = t + i * 512;
          pf[i] = *(const float4*)(xsrc + (ch >> 5) * 128 + (ch & 31) * 4);
        }
      }
      wait_for(cA, 16u * (it + 1));
      float* Ub = U_g + ((b * 2 + par) << 10) + sl * 128;
      float* ssb = SS_g + (b * 2 + par) * 8;
      // stage 1: read U + SS, zero them (t<128) | gh = Whh@hprev + bhh (t>=128)
      if (t < 128) {
        float uv = gload(&Ub[t]);
        sb.Uk[CPAD(t)] = uv;
        gstore(&Ub[t], 0.f);
        if (t == 0) { sb.red[14] = gload(&ssb[sl]); gstore(&ssb[sl], 0.f); }
      } else {
        int r = t - 128;
        sb.gh[r] = dot128f(Whh + (long)r * 128, slot_sh, bhh[r]);
      }
      lbar();
      // stage 2: gi_raw = Wiv @ U   (k-split: 512 threads, 3 rows each, shfl reduce)
      {
        int c = t & 3, rb = t >> 2;
        float4 uv[8];
#pragma unroll
        for (int q = 0; q < 8; ++q) uv[q] = *(const float4*)&sb.Uk[c * 36 + q * 4];
#pragma unroll
        for (int g = 0; g < 3; ++g) {
          int r = rb + g * 128;
          const float4* wr = (const float4*)(Wiv + (long)r * 128 + c * 32);
          float acc = 0.f;
#pragma unroll
          for (int q = 0; q < 8; ++q) {
            float4 wv = wr[q];
            acc += wv.x * uv[q].x + wv.y * uv[q].y + wv.z * uv[q].z + wv.w * uv[q].w;
          }
          acc += __shfl_down(acc, 2); acc += __shfl_down(acc, 1);
          if (c == 0) sb.gi[r] = acc;
        }
      }
      lbar();
      // stage 3: gates -> hn   (gi = gi_raw/SS + bihv)
      float hnew = 0.f;
      if (t < 128) {
        float invss = 1.f / sb.red[14];
        float gr = sigm(sb.gi[t] * invss + bihv[t] + sb.gh[t]);
        float gz = sigm(sb.gi[128 + t] * invss + bihv[128 + t] + sb.gh[128 + t]);
        float gn = tanh_f(sb.gi[256 + t] * invss + bihv[256 + t] + gr * sb.gh[256 + t]);
        hnew = (1.f - gz) * gn + gz * slot_sh[t];
        sb.hn[t] = hnew;
      }
      // stage 4: LN_ff(hn) -> buf (stats128 has internal lbars)
      float m, inv;
      stats128(hnew, t, sb.red, m, inv);
      if (t < 128) sb.buf[CPAD(t)] = (hnew - m) * inv * g_ff[t] + be_ff[t];
      lbar();
      // stage 5: hid = relu(W1@buf + b1)  (k-split)
      {
        int c = t & 3, r = t >> 2;
        const float4* wr = (const float4*)(W1 + r * 128 + c * 32);
        float acc = 0.f;
#pragma unroll
        for (int q = 0; q < 8; ++q) {
          float4 wv = wr[q];
          float4 vv = *(const float4*)&sb.buf[c * 36 + q * 4];
          acc += wv.x * vv.x + wv.y * vv.y + wv.z * vv.z + wv.w * vv.w;
        }
        acc += __shfl_down(acc, 2); acc += __shfl_down(acc, 1);
        if (c == 0) sb.hid[CPAD(r)] = fmaxf(acc + b1[r], 0.f);
      }
      lbar();
      // stage 6: sn = hn + W2@hid + b2  (k-split) -> slot_sh
      {
        int c = t & 3, r = t >> 2;
        const float4* wr = (const float4*)(W2 + r * 128 + c * 32);
        float acc = 0.f;
#pragma unroll
        for (int q = 0; q < 8; ++q) {
          float4 wv = wr[q];
          float4 vv = *(const float4*)&sb.hid[c * 36 + q * 4];
          acc += wv.x * vv.x + wv.y * vv.y + wv.z * vv.z + wv.w * vv.w;
        }
        acc += __shfl_down(acc, 2); acc += __shfl_down(acc, 1);
        if (c == 0) slot_sh[r] = sb.hn[r] + acc + b2[r];
      }
      // stage 7: next-frame q projection (starts with internal stats barrier) + announce
      if (it < 16) {
        q_project_pub(sb, slot_sh, g_sl, be_sl, Wqk, bqk, wqbk, bqbk, qW_g, qb_g, b, sl, t);
        arrive(cB);
      } else {
        lbar();
      }
      // deferred slots store
      if (wo && t < 128)
        out_slots[(((long)b * NF_ + f) * S_ + sl) * D_ + t] = slot_sh[t];
      // stage next frame (loads issued before wait_for -> long since landed)
      if (it && it < 16) stage_norm(pf, sa.Xt, g4, b4, t);
    } else {
      // non-B: prefetch + stage next frame while B-chain runs
      if (it && it < 16) {
        const float* xsrc = x + (((long)b * NF_ + it) * N_ + jt * 64) * D_;
#pragma unroll
        for (int i = 0; i < 4; ++i) {
          int ch = t + i * 512;
          pf[i] = *(const float4*)(xsrc + (ch >> 5) * 128 + (ch & 31) * 4);
        }
        stage_norm(pf, sa.Xt, g4, b4, t);
      }
    }
  }
}

extern "C" void kernel_launch(void* const* d_in, const int* in_sizes, int n_in,
                              void* d_out, int out_size, void* d_ws, size_t ws_size,
                              hipStream_t stream) {
  const float* inputs     = (const float*)d_in[0];
  const float* slots_init = (const float*)d_in[1];
  const float* Wq  = (const float*)d_in[2];
  const float* bq  = (const float*)d_in[3];
  const float* Wk  = (const float*)d_in[4];
  const float* bk  = (const float*)d_in[5];
  const float* Wv  = (const float*)d_in[6];
  const float* bv  = (const float*)d_in[7];
  const float* W1  = (const float*)d_in[8];
  const float* b1  = (const float*)d_in[9];
  const float* W2  = (const float*)d_in[10];
  const float* b2  = (const float*)d_in[11];
  const float* Wih = (const float*)d_in[12];
  const float* Whh = (const float*)d_in[13];
  const float* bih = (const float*)d_in[14];
  const float* bhh = (const float*)d_in[15];
  const float* g_in  = (const float*)d_in[16];
  const float* be_in = (const float*)d_in[17];
  const float* g_sl  = (const float*)d_in[18];
  const float* be_sl = (const float*)d_in[19];
  const float* g_ff  = (const float*)d_in[20];
  const float* be_ff = (const float*)d_in[21];

  float* out_slots = (float*)d_out;
  float* out_attn  = out_slots + (size_t)B_ * NF_ * S_ * D_;

  char* ws = (char*)d_ws;
  unsigned* cntA = (unsigned*)ws;                    // 16 counters, 256 B apart (4 KB)
  unsigned* cntB = (unsigned*)(ws + 4096);           // 4 KB
  float* U_g   = (float*)(ws + 8192);                // [16][2][1024] = 131072 -> 139264
  float* SS_g  = (float*)(ws + 139264);              // [16][2][8]    = 1024   -> 140288
  float* Wiv   = (float*)(ws + 140288);              // 196608 -> 336896
  float* bihv  = (float*)(ws + 336896);              // 1536   -> 338432
  float* WqkW  = (float*)(ws + 338432);              // 65536  -> 403968
  float* bqk   = (float*)(ws + 403968);              // 512    -> 404480
  float* wqbk  = (float*)(ws + 404480);              // 512    -> 404992
  float* bqbk  = (float*)(ws + 404992);              // 256    -> 405248
  float* qW_g  = (float*)(ws + 405248);              // 65536  -> 470784
  float* qb_g  = (float*)(ws + 470784);              // 512    -> 471296

  hipMemsetAsync(d_ws, 0, 140288, stream);  // counters + U/SS accumulators

  precomp<<<512, 128, 0, stream>>>(Wih, bih, Wv, bv, Wq, bq, Wk, bk,
                                   Wiv, bihv, WqkW, bqk, wqbk, bqbk);
  slot_persist<<<NB, NT, 0, stream>>>(inputs, slots_init, Whh, bhh,
      W1, b1, W2, b2, g_in, be_in, g_sl, be_sl, g_ff, be_ff,
      Wiv, bihv, WqkW, bqk, wqbk, bqbk,
      out_slots, out_attn, cntA, cntB, U_g, SS_g, qW_g, qb_g);
}

// Round 8
// 661.781 us; speedup vs baseline: 1.3401x; 1.1132x over previous
//
#include <hip/hip_runtime.h>

#define B_ 16
#define NF_ 16
#define N_ 1024
#define D_ 128
#define S_ 8
#define SCALE_ 0.08838834764831845f
#define NB 256
#define NT 512
// scalar index into chunk-padded [4][36] vectors (chunk c = i>>5 at offset c*36)
#define CPAD(i) ((((i) >> 5) * 36) + ((i) & 31))
// full 5-bit XOR swizzle: logical float4-group k of row r lives at group ((k^r)&31)
// (measured round 7: zero bank conflicts at all access sites)
#define XSW(r, k) (((r) * 128) + ((((k) ^ (r)) & 31) << 2))

struct SmemA {
  float Xt[64 * 128];       // NORMALIZED x-hat, swizzled per XSW
  float at[8 * 64];         // dots, then attn (incl +eps)
  float qWs[1024];          // SCALE-prefolded qW, slot-major
  float qbs[8];
};
struct SmemB {              // phase-B scratch
  float Uk[144];            // chunk-padded U vector
  float gh[384];
  float gi[384];
  float hn[128];
  float buf[144], hid[144], nrm[144];
  float red[16];
};

// ---- fence-free device-coherent accessors (proven across 612..483us kernels) ----
__device__ __forceinline__ float gload(const float* p) {
  return __hip_atomic_load(p, __ATOMIC_RELAXED, __HIP_MEMORY_SCOPE_AGENT);
}
__device__ __forceinline__ void gstore(float* p, float v) {
  __hip_atomic_store(p, v, __ATOMIC_RELAXED, __HIP_MEMORY_SCOPE_AGENT);
}
__device__ __forceinline__ void arrive(unsigned* c) {
  __syncthreads();
  if (threadIdx.x == 0) {
    __builtin_amdgcn_s_waitcnt(0);
    __hip_atomic_fetch_add(c, 1u, __ATOMIC_RELAXED, __HIP_MEMORY_SCOPE_AGENT);
  }
}
__device__ __forceinline__ void wait_for(unsigned* c, unsigned target) {
  if (threadIdx.x == 0) {
    while (__hip_atomic_load(c, __ATOMIC_RELAXED, __HIP_MEMORY_SCOPE_AGENT) < target)
      __builtin_amdgcn_s_sleep(1);
  }
  __syncthreads();
}

__device__ __forceinline__ float dot128f(const float* __restrict__ wrow, const float* x, float acc) {
  const float4* w = (const float4*)wrow;
#pragma unroll
  for (int i = 0; i < 32; ++i) {
    float4 v = w[i];
    const float4 xv = *(const float4*)(x + i * 4);
    acc += v.x * xv.x + v.y * xv.y + v.z * xv.z + v.w * xv.w;
  }
  return acc;
}

// Block-wide mean/rsqrt over 128 values held by t<128. ALL threads call.
__device__ __forceinline__ void stats128(float v, int t, float* red, float& m, float& inv) {
  __syncthreads();
  float s = (t < 128) ? v : 0.f;
  float s2 = (t < 128) ? v * v : 0.f;
#pragma unroll
  for (int off = 32; off; off >>= 1) { s += __shfl_down(s, off); s2 += __shfl_down(s2, off); }
  if (t == 0)  { red[0] = s; red[2] = s2; }
  if (t == 64) { red[1] = s; red[3] = s2; }
  __syncthreads();
  m = (red[0] + red[1]) * (1.f / 128.f);
  float var = (red[2] + red[3]) * (1.f / 128.f) - m * m;
  inv = rsqrtf(var + 1e-5f);
}

__device__ __forceinline__ float sigm(float x) { return 1.f / (1.f + __expf(-x)); }
__device__ __forceinline__ float tanh_f(float x) { return 1.f - 2.f / (1.f + __expf(2.f * x)); }

// stage NORMALIZED tile (swizzled); runs in the prefetch window (no trailing barrier).
__device__ __forceinline__ void stage_norm(const float4* pf, float* Xt,
                                           float4 g4, float4 b4, int t) {
  float s1[4], s2[4];
#pragma unroll
  for (int i = 0; i < 4; ++i) {
    s1[i] = pf[i].x + pf[i].y + pf[i].z + pf[i].w;
    s2[i] = pf[i].x * pf[i].x + pf[i].y * pf[i].y + pf[i].z * pf[i].z + pf[i].w * pf[i].w;
  }
#pragma unroll
  for (int mk = 16; mk; mk >>= 1) {
#pragma unroll
    for (int i = 0; i < 4; ++i) { s1[i] += __shfl_xor(s1[i], mk); s2[i] += __shfl_xor(s2[i], mk); }
  }
  int kg = t & 31;
#pragma unroll
  for (int i = 0; i < 4; ++i) {
    int r = (t >> 5) + i * 16;
    float m = s1[i] * (1.f / 128.f);
    float inv = rsqrtf(s2[i] * (1.f / 128.f) - m * m + 1e-5f);
    float4 v = pf[i];
    v.x = (v.x - m) * inv * g4.x + b4.x;
    v.y = (v.y - m) * inv * g4.y + b4.y;
    v.z = (v.z - m) * inv * g4.z + b4.z;
    v.w = (v.w - m) * inv * g4.w + b4.w;
    *(float4*)&Xt[XSW(r, kg)] = v;
  }
}

// slot -> LN_sl -> qW = SCALE*(Wqk@nrm + bqk), qb = SCALE*(wqbk.nrm + bqbk); k-split matvec
__device__ void q_project_pub(SmemB& Bm, const float* slot,
    const float* __restrict__ g_sl, const float* __restrict__ be_sl,
    const float* __restrict__ Wqk, const float* __restrict__ bqk,
    const float* __restrict__ wqbk, const float* __restrict__ bqbk,
    float* qW_g, float* qb_g, int b, int sl, int t) {
  float m, inv;
  float sv = (t < 128) ? slot[t] : 0.f;
  stats128(sv, t, Bm.red, m, inv);
  if (t < 128) {
    float nv = (sv - m) * inv * g_sl[t] + be_sl[t];
    Bm.nrm[CPAD(t)] = nv;
    float qp = wqbk[t] * nv;
#pragma unroll
    for (int off = 32; off; off >>= 1) qp += __shfl_down(qp, off);
    if (t == 0)  Bm.red[4] = qp;
    if (t == 64) Bm.red[5] = qp;
  }
  __syncthreads();
  {
    int c = t & 3, r = t >> 2;
    const float4* wr = (const float4*)(Wqk + r * 128 + c * 32);
    float acc = 0.f;
#pragma unroll
    for (int q = 0; q < 8; ++q) {
      float4 wv = wr[q];
      float4 vv = *(const float4*)&Bm.nrm[c * 36 + q * 4];
      acc += wv.x * vv.x + wv.y * vv.y + wv.z * vv.z + wv.w * vv.w;
    }
    acc += __shfl_down(acc, 2); acc += __shfl_down(acc, 1);
    if (c == 0) gstore(&qW_g[b * 1024 + sl * 128 + r], (acc + bqk[r]) * SCALE_);
  }
  if (t == 0) gstore(&qb_g[b * 8 + sl], (Bm.red[4] + Bm.red[5] + bqbk[0]) * SCALE_);
}

// one-shot algebraic folds (harness-verified rounds 1-7)
__global__ __launch_bounds__(128) void precomp(
    const float* __restrict__ Wih, const float* __restrict__ bih,
    const float* __restrict__ Wv, const float* __restrict__ bv,
    const float* __restrict__ Wq, const float* __restrict__ bq,
    const float* __restrict__ Wk, const float* __restrict__ bk,
    float* Wiv, float* bihv, float* Wqk, float* bqk, float* wqbk, float* bqbk) {
  __shared__ float r2[2];
  int r = blockIdx.x, t = threadIdx.x;
  if (r < 384) {
    float acc = 0.f;
#pragma unroll 8
    for (int k = 0; k < 128; ++k) acc += Wih[r * 128 + k] * Wv[k * 128 + t];
    Wiv[r * 128 + t] = acc;
    float p = Wih[r * 128 + t] * bv[t];
#pragma unroll
    for (int off = 32; off; off >>= 1) p += __shfl_down(p, off);
    if ((t & 63) == 0) r2[t >> 6] = p;
    __syncthreads();
    if (t == 0) bihv[r] = r2[0] + r2[1] + bih[r];
  } else {
    int c = r - 384;
    float acc = 0.f;
#pragma unroll 8
    for (int dd = 0; dd < 128; ++dd) acc += Wk[dd * 128 + c] * Wq[dd * 128 + t];
    Wqk[c * 128 + t] = acc;
    float p = Wk[t * 128 + c] * bq[t];
#pragma unroll
    for (int off = 32; off; off >>= 1) p += __shfl_down(p, off);
    if ((t & 63) == 0) r2[t >> 6] = p;
    __syncthreads();
    if (t == 0) bqk[c] = r2[0] + r2[1];
    if (c == 0) {
      float a2 = 0.f;
#pragma unroll 8
      for (int dd = 0; dd < 128; ++dd) a2 += Wq[dd * 128 + t] * bk[dd];
      wqbk[t] = a2;
      float p2 = bq[t] * bk[t];
#pragma unroll
      for (int off = 32; off; off >>= 1) p2 += __shfl_down(p2, off);
      __syncthreads();
      if ((t & 63) == 0) r2[t >> 6] = p2;
      __syncthreads();
      if (t == 0) bqbk[0] = r2[0] + r2[1];
    }
  }
}

__global__ __launch_bounds__(NT) void slot_persist(
    const float* __restrict__ x, const float* __restrict__ slots_init,
    const float* __restrict__ Whh, const float* __restrict__ bhh,
    const float* __restrict__ W1, const float* __restrict__ b1,
    const float* __restrict__ W2, const float* __restrict__ b2,
    const float* __restrict__ g_in, const float* __restrict__ be_in,
    const float* __restrict__ g_sl, const float* __restrict__ be_sl,
    const float* __restrict__ g_ff, const float* __restrict__ be_ff,
    const float* __restrict__ Wiv, const float* __restrict__ bihv,
    const float* __restrict__ Wqk, const float* __restrict__ bqk,
    const float* __restrict__ wqbk, const float* __restrict__ bqbk,
    float* out_slots, float* out_attn,
    unsigned* cntA, unsigned* cntB,
    float* U_g, float* SS_g, float* qW_g, float* qb_g) {
  __shared__ __align__(16) SmemA sa;
  __shared__ __align__(16) SmemB sb;
  __shared__ __align__(16) float slot_sh[128];
  int t = threadIdx.x, bid = blockIdx.x;
  int b = bid >> 4, jt = bid & 15;
  bool isB = (jt < 8);
  unsigned* cA = cntA + (b << 6);
  unsigned* cB = cntB + (b << 6);
  int s = t >> 6, j = t & 63;

  const float4 g4 = *(const float4*)(g_in + (t & 31) * 4);
  const float4 b4 = *(const float4*)(be_in + (t & 31) * 4);

  if (isB) {
    if (t < 128) slot_sh[t] = slots_init[jt * 128 + t];
    q_project_pub(sb, slot_sh, g_sl, be_sl, Wqk, bqk, wqbk, bqbk, qW_g, qb_g, b, jt, t);
    arrive(cB);
  }
  float4 pf[4];
  {
    const float* xsrc = x + (((long)b * NF_ + 0) * N_ + jt * 64) * D_;
#pragma unroll
    for (int i = 0; i < 4; ++i) {
      int ch = t + i * 512;
      pf[i] = *(const float4*)(xsrc + (ch >> 5) * 128 + (ch & 31) * 4);
    }
  }
  stage_norm(pf, sa.Xt, g4, b4, t);   // frame 0; barrier = loop-top wait_for

  for (int it = 0; it < 17; ++it) {
    int f = (it == 0) ? 0 : it - 1;
    int wo = it > 0;
    int par = it & 1;
    // ---- wait for qW of this frame ----
    wait_for(cB, 8u * (it + 1));
    sa.qWs[t] = gload(&qW_g[b * 1024 + t]);
    sa.qWs[512 + t] = gload(&qW_g[b * 1024 + 512 + t]);
    if (t < 8) sa.qbs[t] = gload(&qb_g[b * 8 + t]);
    __syncthreads();
    // ---- dots on normalized X (full-XOR swizzle, conflict-free b128) ----
    {
      const float4* qq4 = (const float4*)(sa.qWs + s * 128);
      float d = 0.f;
#pragma unroll
      for (int k4 = 0; k4 < 32; ++k4) {
        float4 xv = *(const float4*)&sa.Xt[XSW(j, k4)];
        float4 qv = qq4[k4];
        d += xv.x * qv.x + xv.y * qv.y + xv.z * qv.z + xv.w * qv.w;
      }
      sa.at[s * 64 + j] = d + sa.qbs[s];
    }
    __syncthreads();
    // ---- softmax over slots (per column j = t < 64); stores deferred ----
    float vals[8];
    if (t < 64) {
      float mx = -1e30f;
#pragma unroll
      for (int ss = 0; ss < 8; ++ss) { vals[ss] = sa.at[ss * 64 + t]; mx = fmaxf(mx, vals[ss]); }
      float sum = 0.f;
#pragma unroll
      for (int ss = 0; ss < 8; ++ss) { vals[ss] = __expf(vals[ss] - mx); sum += vals[ss]; }
      float rr = 1.f / sum;
#pragma unroll
      for (int ss = 0; ss < 8; ++ss) { vals[ss] = vals[ss] * rr + 1e-8f; sa.at[ss * 64 + t] = vals[ss]; }
    }
    __syncthreads();
    // ---- SS partials (wave = slot), device atomics ----
    {
      float v = sa.at[s * 64 + j];
#pragma unroll
      for (int off = 32; off; off >>= 1) v += __shfl_down(v, off);
      if (j == 0) atomicAdd(&SS_g[(b * 2 + par) * 8 + s], v);
    }
    // ---- U partials: round-5 coalesced pattern, X reads adapted to XSW (<=2-way) ----
    {
      int k2 = t & 127, h = t >> 7;
      int dg = k2 >> 2, dr = k2 & 3;
      float u0 = 0.f, u1 = 0.f;
      const float* a0 = sa.at + h * 64;
      const float* a1 = sa.at + (h + 4) * 64;
#pragma unroll
      for (int j0 = 0; j0 < 64; j0 += 4) {
        float4 av0 = *(const float4*)(a0 + j0);
        float4 av1 = *(const float4*)(a1 + j0);
        float x0 = sa.Xt[XSW(j0 + 0, dg) + dr];
        float x1 = sa.Xt[XSW(j0 + 1, dg) + dr];
        float x2 = sa.Xt[XSW(j0 + 2, dg) + dr];
        float x3 = sa.Xt[XSW(j0 + 3, dg) + dr];
        u0 += av0.x * x0 + av0.y * x1 + av0.z * x2 + av0.w * x3;
        u1 += av1.x * x0 + av1.y * x1 + av1.z * x2 + av1.w * x3;
      }
      float* Ub = U_g + ((b * 2 + par) << 10);
      atomicAdd(&Ub[h * 128 + k2], u0);
      atomicAdd(&Ub[(h + 4) * 128 + k2], u1);
    }
    arrive(cA);
    // ---- deferred attn stores (drain during next wait's poll) ----
    if (wo && t < 64) {
#pragma unroll
      for (int ss = 0; ss < 8; ++ss)
        out_attn[(((long)b * NF_ + f) * S_ + ss) * N_ + jt * 64 + t] = vals[ss];
    }
    // ================= phase B (blocks jt<8: slot s=jt of batch b) =================
    if (isB) {
      int sl = jt;
      // issue next-frame x loads NOW: HBM latency hides under the poll + B-chain
      if (it && it < 16) {
        const float* xsrc = x + (((long)b * NF_ + it) * N_ + jt * 64) * D_;
#pragma unroll
        for (int i = 0; i < 4; ++i) {
          int ch = t + i * 512;
          pf[i] = *(const float4*)(xsrc + (ch >> 5) * 128 + (ch & 31) * 4);
        }
      }
      wait_for(cA, 16u * (it + 1));
      float* Ub = U_g + ((b * 2 + par) << 10) + sl * 128;
      float* ssb = SS_g + (b * 2 + par) * 8;
      // stage 1: read U + SS, zero them (t<128) | gh = Whh@hprev + bhh (t>=128)
      if (t < 128) {
        float uv = gload(&Ub[t]);
        sb.Uk[CPAD(t)] = uv;
        gstore(&Ub[t], 0.f);
        if (t == 0) { sb.red[14] = gload(&ssb[sl]); gstore(&ssb[sl], 0.f); }
      } else {
        int r = t - 128;
        sb.gh[r] = dot128f(Whh + (long)r * 128, slot_sh, bhh[r]);
      }
      __syncthreads();
      // stage 2: gi_raw = Wiv @ U   (k-split: 512 threads, 3 rows each, shfl reduce)
      {
        int c = t & 3, rb = t >> 2;
        float4 uv[8];
#pragma unroll
        for (int q = 0; q < 8; ++q) uv[q] = *(const float4*)&sb.Uk[c * 36 + q * 4];
#pragma unroll
        for (int g = 0; g < 3; ++g) {
          int r = rb + g * 128;
          const float4* wr = (const float4*)(Wiv + (long)r * 128 + c * 32);
          float acc = 0.f;
#pragma unroll
          for (int q = 0; q < 8; ++q) {
            float4 wv = wr[q];
            acc += wv.x * uv[q].x + wv.y * uv[q].y + wv.z * uv[q].z + wv.w * uv[q].w;
          }
          acc += __shfl_down(acc, 2); acc += __shfl_down(acc, 1);
          if (c == 0) sb.gi[r] = acc;
        }
      }
      __syncthreads();
      // stage 3: gates -> hn   (gi = gi_raw/SS + bihv)
      float hnew = 0.f;
      if (t < 128) {
        float invss = 1.f / sb.red[14];
        float gr = sigm(sb.gi[t] * invss + bihv[t] + sb.gh[t]);
        float gz = sigm(sb.gi[128 + t] * invss + bihv[128 + t] + sb.gh[128 + t]);
        float gn = tanh_f(sb.gi[256 + t] * invss + bihv[256 + t] + gr * sb.gh[256 + t]);
        hnew = (1.f - gz) * gn + gz * slot_sh[t];
        sb.hn[t] = hnew;
      }
      // stage 4: LN_ff(hn) -> buf (chunk-padded; stats128 syncs internally)
      float m, inv;
      stats128(hnew, t, sb.red, m, inv);
      if (t < 128) sb.buf[CPAD(t)] = (hnew - m) * inv * g_ff[t] + be_ff[t];
      __syncthreads();
      // stage 5: hid = relu(W1@buf + b1)  (k-split)
      {
        int c = t & 3, r = t >> 2;
        const float4* wr = (const float4*)(W1 + r * 128 + c * 32);
        float acc = 0.f;
#pragma unroll
        for (int q = 0; q < 8; ++q) {
          float4 wv = wr[q];
          float4 vv = *(const float4*)&sb.buf[c * 36 + q * 4];
          acc += wv.x * vv.x + wv.y * vv.y + wv.z * vv.z + wv.w * vv.w;
        }
        acc += __shfl_down(acc, 2); acc += __shfl_down(acc, 1);
        if (c == 0) sb.hid[CPAD(r)] = fmaxf(acc + b1[r], 0.f);
      }
      __syncthreads();
      // stage 6: sn = hn + W2@hid + b2  (k-split) -> slot_sh
      {
        int c = t & 3, r = t >> 2;
        const float4* wr = (const float4*)(W2 + r * 128 + c * 32);
        float acc = 0.f;
#pragma unroll
        for (int q = 0; q < 8; ++q) {
          float4 wv = wr[q];
          float4 vv = *(const float4*)&sb.hid[c * 36 + q * 4];
          acc += wv.x * vv.x + wv.y * vv.y + wv.z * vv.z + wv.w * vv.w;
        }
        acc += __shfl_down(acc, 2); acc += __shfl_down(acc, 1);
        if (c == 0) slot_sh[r] = sb.hn[r] + acc + b2[r];
      }
      // stage 7: next-frame q projection (starts with internal stats barrier) + announce
      if (it < 16) {
        q_project_pub(sb, slot_sh, g_sl, be_sl, Wqk, bqk, wqbk, bqbk, qW_g, qb_g, b, sl, t);
        arrive(cB);
      } else {
        __syncthreads();
      }
      // deferred slots store
      if (wo && t < 128)
        out_slots[(((long)b * NF_ + f) * S_ + sl) * D_ + t] = slot_sh[t];
      // stage next frame (loads issued before wait_for -> long since landed)
      if (it && it < 16) stage_norm(pf, sa.Xt, g4, b4, t);
    } else {
      // non-B: prefetch + stage next frame while B-chain runs
      if (it && it < 16) {
        const float* xsrc = x + (((long)b * NF_ + it) * N_ + jt * 64) * D_;
#pragma unroll
        for (int i = 0; i < 4; ++i) {
          int ch = t + i * 512;
          pf[i] = *(const float4*)(xsrc + (ch >> 5) * 128 + (ch & 31) * 4);
        }
        stage_norm(pf, sa.Xt, g4, b4, t);
      }
    }
  }
}

extern "C" void kernel_launch(void* const* d_in, const int* in_sizes, int n_in,
                              void* d_out, int out_size, void* d_ws, size_t ws_size,
                              hipStream_t stream) {
  const float* inputs     = (const float*)d_in[0];
  const float* slots_init = (const float*)d_in[1];
  const float* Wq  = (const float*)d_in[2];
  const float* bq  = (const float*)d_in[3];
  const float* Wk  = (const float*)d_in[4];
  const float* bk  = (const float*)d_in[5];
  const float* Wv  = (const float*)d_in[6];
  const float* bv  = (const float*)d_in[7];
  const float* W1  = (const float*)d_in[8];
  const float* b1  = (const float*)d_in[9];
  const float* W2  = (const float*)d_in[10];
  const float* b2  = (const float*)d_in[11];
  const float* Wih = (const float*)d_in[12];
  const float* Whh = (const float*)d_in[13];
  const float* bih = (const float*)d_in[14];
  const float* bhh = (const float*)d_in[15];
  const float* g_in  = (const float*)d_in[16];
  const float* be_in = (const float*)d_in[17];
  const float* g_sl  = (const float*)d_in[18];
  const float* be_sl = (const float*)d_in[19];
  const float* g_ff  = (const float*)d_in[20];
  const float* be_ff = (const float*)d_in[21];

  float* out_slots = (float*)d_out;
  float* out_attn  = out_slots + (size_t)B_ * NF_ * S_ * D_;

  char* ws = (char*)d_ws;
  unsigned* cntA = (unsigned*)ws;                    // 16 counters, 256 B apart (4 KB)
  unsigned* cntB = (unsigned*)(ws + 4096);           // 4 KB
  float* U_g   = (float*)(ws + 8192);                // [16][2][1024] = 131072 -> 139264
  float* SS_g  = (float*)(ws + 139264);              // [16][2][8]    = 1024   -> 140288
  float* Wiv   = (float*)(ws + 140288);              // 196608 -> 336896
  float* bihv  = (float*)(ws + 336896);              // 1536   -> 338432
  float* WqkW  = (float*)(ws + 338432);              // 65536  -> 403968
  float* bqk   = (float*)(ws + 403968);              // 512    -> 404480
  float* wqbk  = (float*)(ws + 404480);              // 512    -> 404992
  float* bqbk  = (float*)(ws + 404992);              // 256    -> 405248
  float* qW_g  = (float*)(ws + 405248);              // 65536  -> 470784
  float* qb_g  = (float*)(ws + 470784);              // 512    -> 471296

  hipMemsetAsync(d_ws, 0, 140288, stream);  // counters + U/SS accumulators

  precomp<<<512, 128, 0, stream>>>(Wih, bih, Wv, bv, Wq, bq, Wk, bk,
                                   Wiv, bihv, WqkW, bqk, wqbk, bqbk);
  slot_persist<<<NB, NT, 0, stream>>>(inputs, slots_init, Whh, bhh,
      W1, b1, W2, b2, g_in, be_in, g_sl, be_sl, g_ff, be_ff,
      Wiv, bihv, WqkW, bqk, wqbk, bqbk,
      out_slots, out_attn, cntA, cntB, U_g, SS_g, qW_g, qb_g);
}